// Round 22
// baseline (231.386 us; speedup 1.0000x reference)
//
#include <hip/hip_runtime.h>
#include <stdint.h>

typedef unsigned short u16;
typedef __bf16 bf16x8 __attribute__((ext_vector_type(8)));
typedef float f32x4 __attribute__((ext_vector_type(4)));
typedef float f32x16 __attribute__((ext_vector_type(16)));
typedef unsigned int uint2v __attribute__((ext_vector_type(2)));

#define S_LEN 2048
#define D_MODEL 1024

struct TrueT  { static constexpr bool value = true;  };
struct FalseT { static constexpr bool value = false; };

__device__ __forceinline__ u16 f2b(float f) {
    uint32_t u = __float_as_uint(f);
    u += 0x7FFFu + ((u >> 16) & 1u);   // round-to-nearest-even
    return (u16)(u >> 16);
}

__device__ __forceinline__ float b2f(u16 b) {
    uint32_t u = (uint32_t)b << 16;
    return __uint_as_float(u);
}

__device__ __forceinline__ uint32_t pk2(float a, float b) {
    union { struct { __bf16 l, h; } s; uint32_t u; } c;
    c.s.l = (__bf16)a; c.s.h = (__bf16)b; return c.u;
}

__device__ __forceinline__ float fexp2(float x) {
#if __has_builtin(__builtin_amdgcn_exp2f)
    return __builtin_amdgcn_exp2f(x);
#else
    return exp2f(x);
#endif
}

// permlane32_swap(a,b) -> {new_a, new_b}
__device__ __forceinline__ uint2v plswap(uint32_t a, uint32_t b) {
#if __has_builtin(__builtin_amdgcn_permlane32_swap)
    return __builtin_amdgcn_permlane32_swap(a, b, false, false);
#else
    uint2v r;
    uint32_t pa = (uint32_t)__shfl_xor((int)a, 32, 64);
    uint32_t pb = (uint32_t)__shfl_xor((int)b, 32, 64);
    const int hi = (threadIdx.x & 63) >> 5;
    r[0] = hi ? pb : a;
    r[1] = hi ? b : pa;
    return r;
#endif
}
__device__ __forceinline__ float xhalf_max(float x) {
    uint2v r = plswap(__float_as_uint(x), __float_as_uint(x));
    return fmaxf(__uint_as_float(r[0]), __uint_as_float(r[1]));
}
__device__ __forceinline__ float xhalf_add(float x) {
    uint2v r = plswap(__float_as_uint(x), __float_as_uint(x));
    return __uint_as_float(r[0]) + __uint_as_float(r[1]);
}

__device__ __forceinline__ void gl16(const void* g, void* l) {
    __builtin_amdgcn_global_load_lds(
        (const __attribute__((address_space(1))) void*)g,
        (__attribute__((address_space(3))) void*)l, 16, 0, 0);
}

// ---------------- elementwise f32 -> bf16 ----------------
__global__ __launch_bounds__(256) void k_convert_bf16(
    const float* __restrict__ in, u16* __restrict__ out, int n)
{
    int i = (blockIdx.x * 256 + threadIdx.x) * 4;
    if (i >= n) return;
    float4 v = *reinterpret_cast<const float4*>(in + i);
    ushort4 o;
    o.x = f2b(v.x); o.y = f2b(v.y); o.z = f2b(v.z); o.w = f2b(v.w);
    *reinterpret_cast<ushort4*>(out + i) = o;
}

// ---------------- W [K,N] f32 -> WT [N,K] bf16 ----------------
__global__ __launch_bounds__(256) void k_transpose_w(
    const float* __restrict__ W, u16* __restrict__ WT, int K, int N)
{
    __shared__ float tile[32][33];
    const int nt = blockIdx.x, kt = blockIdx.y;
    const int tx = threadIdx.x & 31, ty = threadIdx.x >> 5;  // ty 0..7
#pragma unroll
    for (int i = 0; i < 4; ++i)
        tile[ty + i * 8][tx] = W[(long)(kt * 32 + ty + i * 8) * N + nt * 32 + tx];
    __syncthreads();
#pragma unroll
    for (int i = 0; i < 4; ++i)
        WT[(long)(nt * 32 + ty + i * 8) * K + kt * 32 + tx] = f2b(tile[tx][ty + i * 8]);
}

// ---------------- GEMM 256x256, BK=64, counted-vmcnt 4-phase ----------------
// MODE 0 (FF1): out bf16 = relu(val + bias), no split-K.
// MODE 1 (FF2): out bf16 PARTIAL plane z (no bias; k_ln4b folds 4 planes).
// PATCH INVARIANT: va*vb MUST be 8 (xcd 0..7 -> patch (xcd/vb, xcd%vb)).
// Swizzle: f(row) = (row>>1)&3 (full period-8 slot permutation, 0 conflicts).
template <int MODE>
__global__ __launch_bounds__(512, 2) void k_gemm8(
    const u16* __restrict__ A, const u16* __restrict__ BT,
    const float* __restrict__ bias, u16* __restrict__ outb,
    int M, int N, int K, int va, int vb)
{
    __shared__ u16 As[2][2][8192];   // [slot][khalf][256*32]
    __shared__ u16 Bs[2][2][8192];
    const int t = threadIdx.x;
    const int lane = t & 63, wid = t >> 6;      // 8 waves
    const int wm = wid >> 2, wn = wid & 3;
    const int lr = lane & 15, lg = lane >> 4;

    const int GX = gridDim.x, GY = gridDim.y;
    const int dd = blockIdx.y * GX + blockIdx.x;
    const int xcd = dd & 7, ii = dd >> 3;
    const int hb = GY / va, wb = GX / vb;
    const int by = (xcd / vb) * hb + ii / wb;
    const int bx = (xcd % vb) * wb + ii % wb;
    const int m0 = by * 256, n0 = bx * 256;

    const int Kc = K / (int)gridDim.z;
    const long koff = (long)blockIdx.z * Kc;
    const int NT = Kc >> 6;

    auto STAGEU = [&](const u16* __restrict__ P, int rbase, u16* lds_unit,
                      int tt, int kh) {
        const int ko = tt * 64 + kh * 32;
#pragma unroll
        for (int s = 0; s < 2; ++s) {
            const int c = wid * 64 + lane + s * 512;
            const int op = c * 16;
            const int row = op >> 6;
            const int kg = ((op >> 4) & 3) ^ ((row >> 1) & 3);
            gl16(P + (long)(rbase + row) * K + koff + ko + kg * 8,
                 (char*)lds_unit + op);
        }
    };
    auto RD = [&](const u16* unit, int rb) -> bf16x8 {
        const int row = rb + lr;
        const int op = (row * 64 + lg * 16) ^ (((row >> 1) & 3) << 4);
        return *reinterpret_cast<const bf16x8*>((const char*)unit + op);
    };

    f32x4 acc[8][4];
#pragma unroll
    for (int i = 0; i < 8; ++i)
#pragma unroll
        for (int j = 0; j < 4; ++j) acc[i][j] = (f32x4){0.f, 0.f, 0.f, 0.f};

    STAGEU(A, m0, &As[0][0][0], 0, 0);
    STAGEU(BT, n0, &Bs[0][0][0], 0, 0);
    STAGEU(A, m0, &As[0][1][0], 0, 1);
    STAGEU(BT, n0, &Bs[0][1][0], 0, 1);
    STAGEU(A, m0, &As[1][0][0], 1, 0);
    STAGEU(BT, n0, &Bs[1][0][0], 1, 0);
    asm volatile("s_waitcnt vmcnt(0)" ::: "memory");
    __builtin_amdgcn_s_barrier();

    for (int tt = 0; tt < NT; ++tt) {
        const int sl = tt & 1;
        bf16x8 af[4], bfr[4];

        // ---- phase 0: kh0, row-half 0 ----
#pragma unroll
        for (int rf = 0; rf < 4; ++rf)
            af[rf] = RD(&As[sl][0][0], wm * 128 + rf * 16);
#pragma unroll
        for (int cf = 0; cf < 4; ++cf)
            bfr[cf] = RD(&Bs[sl][0][0], wn * 64 + cf * 16);
        if (tt + 1 < NT) STAGEU(A, m0, &As[sl ^ 1][1][0], tt + 1, 1);
        __builtin_amdgcn_s_setprio(1);
#pragma unroll
        for (int cf = 0; cf < 4; ++cf)
#pragma unroll
            for (int rf = 0; rf < 4; ++rf)
                acc[rf][cf] = __builtin_amdgcn_mfma_f32_16x16x32_bf16(af[rf], bfr[cf], acc[rf][cf], 0, 0, 0);
        __builtin_amdgcn_s_setprio(0);
        __builtin_amdgcn_s_barrier();

        // ---- phase 1: kh0, row-half 1 ----
#pragma unroll
        for (int rf = 0; rf < 4; ++rf)
            af[rf] = RD(&As[sl][0][0], wm * 128 + 64 + rf * 16);
        if (tt + 1 < NT) STAGEU(BT, n0, &Bs[sl ^ 1][1][0], tt + 1, 1);
        __builtin_amdgcn_s_setprio(1);
#pragma unroll
        for (int cf = 0; cf < 4; ++cf)
#pragma unroll
            for (int rf = 0; rf < 4; ++rf)
                acc[4 + rf][cf] = __builtin_amdgcn_mfma_f32_16x16x32_bf16(af[rf], bfr[cf], acc[4 + rf][cf], 0, 0, 0);
        __builtin_amdgcn_s_setprio(0);
        asm volatile("s_waitcnt vmcnt(8)" ::: "memory");
        __builtin_amdgcn_s_barrier();

        // ---- phase 2: kh1, row-half 0 ----
#pragma unroll
        for (int rf = 0; rf < 4; ++rf)
            af[rf] = RD(&As[sl][1][0], wm * 128 + rf * 16);
#pragma unroll
        for (int cf = 0; cf < 4; ++cf)
            bfr[cf] = RD(&Bs[sl][1][0], wn * 64 + cf * 16);
        if (tt + 2 < NT) STAGEU(A, m0, &As[sl][0][0], tt + 2, 0);
        __builtin_amdgcn_s_setprio(1);
#pragma unroll
        for (int cf = 0; cf < 4; ++cf)
#pragma unroll
            for (int rf = 0; rf < 4; ++rf)
                acc[rf][cf] = __builtin_amdgcn_mfma_f32_16x16x32_bf16(af[rf], bfr[cf], acc[rf][cf], 0, 0, 0);
        __builtin_amdgcn_s_setprio(0);
        __builtin_amdgcn_s_barrier();

        // ---- phase 3: kh1, row-half 1 ----
#pragma unroll
        for (int rf = 0; rf < 4; ++rf)
            af[rf] = RD(&As[sl][1][0], wm * 128 + 64 + rf * 16);
        if (tt + 2 < NT) STAGEU(BT, n0, &Bs[sl][0][0], tt + 2, 0);
        __builtin_amdgcn_s_setprio(1);
#pragma unroll
        for (int cf = 0; cf < 4; ++cf)
#pragma unroll
            for (int rf = 0; rf < 4; ++rf)
                acc[4 + rf][cf] = __builtin_amdgcn_mfma_f32_16x16x32_bf16(af[rf], bfr[cf], acc[4 + rf][cf], 0, 0, 0);
        __builtin_amdgcn_s_setprio(0);
        asm volatile("s_waitcnt vmcnt(8)" ::: "memory");
        __builtin_amdgcn_s_barrier();
    }

    // epilogue
    const long zoff = (long)blockIdx.z * M * N;
#pragma unroll
    for (int fr = 0; fr < 8; ++fr)
#pragma unroll
        for (int cf = 0; cf < 4; ++cf) {
            const int n = n0 + wn * 64 + cf * 16 + lr;
            const float bn = (MODE == 0) ? bias[n] : 0.f;
#pragma unroll
            for (int r = 0; r < 4; ++r) {
                const int m = m0 + wm * 128 + fr * 16 + lg * 4 + r;
                if (MODE == 0)
                    outb[(long)m * N + n] = f2b(fmaxf(acc[fr][cf][r] + bn, 0.f));
                else
                    outb[zoff + (long)m * N + n] = f2b(acc[fr][cf][r]);
            }
        }
}

// ---------------- GEMM 256x128, BK=64, counted-vmcnt 2-phase ------
// MODE 0 (OP):  out f32 partial plane z (consumer LN folds bias/resid).
// MODE 1 (QKV): out bf16 scattered to PACKED Q'/K'/V' fragment layouts
//   (bias=bq, bias2=bk, bias3=bv; scatter uses absolute (m,n) only).
// Grid (N/128, M/256, z); patch invariant va*vb = 8. 96KB LDS -> 1 block/CU.
template <int MODE>
__global__ __launch_bounds__(512, 2) void k_gemm8n(
    const u16* __restrict__ A, const u16* __restrict__ BT,
    const float* __restrict__ bias, const float* __restrict__ bias2,
    const float* __restrict__ bias3,
    u16* __restrict__ outb, float* __restrict__ outf,
    int M, int N, int K, int va, int vb)
{
    __shared__ u16 As[2][2][8192];   // [slot][khalf][256 rows * 32 k]
    __shared__ u16 Bs[2][2][4096];   // [slot][khalf][128 rows * 32 k]
    const int t = threadIdx.x;
    const int lane = t & 63, wid = t >> 6;      // 8 waves, 4M x 2N
    const int wm = wid >> 1, wn = wid & 1;
    const int lr = lane & 15, lg = lane >> 4;

    const int GX = gridDim.x, GY = gridDim.y;
    const int dd = blockIdx.y * GX + blockIdx.x;
    const int xcd = dd & 7, ii = dd >> 3;
    const int hb = GY / va, wb = GX / vb;
    const int by = (xcd / vb) * hb + ii / wb;
    const int bx = (xcd % vb) * wb + ii % wb;
    const int m0 = by * 256, n0 = bx * 128;

    const int Kc = K / (int)gridDim.z;
    const long koff = (long)blockIdx.z * Kc;
    const int NT = Kc >> 6;

    auto STAGEA = [&](u16* lds_unit, int tt, int kh) {
        const int ko = tt * 64 + kh * 32;
#pragma unroll
        for (int s = 0; s < 2; ++s) {
            const int c = wid * 64 + lane + s * 512;
            const int op = c * 16;
            const int row = op >> 6;
            const int kg = ((op >> 4) & 3) ^ ((row >> 1) & 3);
            gl16(A + (long)(m0 + row) * K + koff + ko + kg * 8,
                 (char*)lds_unit + op);
        }
    };
    auto STAGEB = [&](u16* lds_unit, int tt, int kh) {
        const int ko = tt * 64 + kh * 32;
        const int c = wid * 64 + lane;
        const int op = c * 16;
        const int row = op >> 6;
        const int kg = ((op >> 4) & 3) ^ ((row >> 1) & 3);
        gl16(BT + (long)(n0 + row) * K + koff + ko + kg * 8,
             (char*)lds_unit + op);
    };
    auto RD = [&](const u16* unit, int rb) -> bf16x8 {
        const int row = rb + lr;
        const int op = (row * 64 + lg * 16) ^ (((row >> 1) & 3) << 4);
        return *reinterpret_cast<const bf16x8*>((const char*)unit + op);
    };

    f32x4 acc[4][4];
#pragma unroll
    for (int i = 0; i < 4; ++i)
#pragma unroll
        for (int j = 0; j < 4; ++j) acc[i][j] = (f32x4){0.f, 0.f, 0.f, 0.f};

    STAGEA(&As[0][0][0], 0, 0); STAGEB(&Bs[0][0][0], 0, 0);
    STAGEA(&As[0][1][0], 0, 1); STAGEB(&Bs[0][1][0], 0, 1);
    STAGEA(&As[1][0][0], 1, 0); STAGEB(&Bs[1][0][0], 1, 0);
    asm volatile("s_waitcnt vmcnt(0)" ::: "memory");
    __builtin_amdgcn_s_barrier();

    for (int tt = 0; tt < NT; ++tt) {
        const int sl = tt & 1;
        bf16x8 af[4], bfr[4];

#pragma unroll
        for (int rf = 0; rf < 4; ++rf)
            af[rf] = RD(&As[sl][0][0], wm * 64 + rf * 16);
#pragma unroll
        for (int cf = 0; cf < 4; ++cf)
            bfr[cf] = RD(&Bs[sl][0][0], wn * 64 + cf * 16);
        if (tt + 1 < NT) {
            STAGEA(&As[sl ^ 1][1][0], tt + 1, 1);
            STAGEB(&Bs[sl ^ 1][1][0], tt + 1, 1);
        }
        __builtin_amdgcn_s_setprio(1);
#pragma unroll
        for (int cf = 0; cf < 4; ++cf)
#pragma unroll
            for (int rf = 0; rf < 4; ++rf)
                acc[rf][cf] = __builtin_amdgcn_mfma_f32_16x16x32_bf16(af[rf], bfr[cf], acc[rf][cf], 0, 0, 0);
        __builtin_amdgcn_s_setprio(0);
        asm volatile("s_waitcnt vmcnt(6)" ::: "memory");
        __builtin_amdgcn_s_barrier();

#pragma unroll
        for (int rf = 0; rf < 4; ++rf)
            af[rf] = RD(&As[sl][1][0], wm * 64 + rf * 16);
#pragma unroll
        for (int cf = 0; cf < 4; ++cf)
            bfr[cf] = RD(&Bs[sl][1][0], wn * 64 + cf * 16);
        if (tt + 2 < NT) {
            STAGEA(&As[sl][0][0], tt + 2, 0);
            STAGEB(&Bs[sl][0][0], tt + 2, 0);
        }
        __builtin_amdgcn_s_setprio(1);
#pragma unroll
        for (int cf = 0; cf < 4; ++cf)
#pragma unroll
            for (int rf = 0; rf < 4; ++rf)
                acc[rf][cf] = __builtin_amdgcn_mfma_f32_16x16x32_bf16(af[rf], bfr[cf], acc[rf][cf], 0, 0, 0);
        __builtin_amdgcn_s_setprio(0);
        asm volatile("s_waitcnt vmcnt(6)" ::: "memory");
        __builtin_amdgcn_s_barrier();
    }

    const long zoff = (long)blockIdx.z * M * N;
#pragma unroll
    for (int fr = 0; fr < 4; ++fr)
#pragma unroll
        for (int cf = 0; cf < 4; ++cf) {
            const int n = n0 + wn * 64 + cf * 16 + lr;
            float bn = 0.f;
            if (MODE == 1)
                bn = (n < 1024) ? bias[n] : (n < 2048) ? bias2[n - 1024] : bias3[n - 2048];
#pragma unroll
            for (int r = 0; r < 4; ++r) {
                const int m = m0 + wm * 64 + fr * 16 + lg * 4 + r;
                if (MODE == 0) {
                    outf[zoff + (long)m * N + n] = acc[fr][cf][r];
                } else {
                    // packed Q'/K'/V' scatter (same math as prior kernels)
                    const float v = acc[fr][cf][r] + bn;
                    const int b = m >> 11, s = m & 2047;
                    const int which = n >> 10, nn = n & 1023;
                    const int h = nn >> 6, dk = nn & 63;
                    const long bhb = (long)(b * 16 + h) * (2048L * 64);
                    const int s32 = s >> 5, sr = s & 31;
                    long addr;
                    if (which < 2) {
                        addr = bhb + (long)s32 * 2048 + (dk >> 4) * 512 +
                               ((dk >> 3) & 1) * 256 + sr * 8 + (dk & 7);
                    } else {
                        addr = bhb + (long)s32 * 2048 + (dk >> 5) * 1024 +
                               ((sr >> 4) & 1) * 512 + ((sr >> 3) & 1) * 256 +
                               (dk & 31) * 8 + (sr & 7);
                    }
                    outb[(long)which * (32L * 2048 * 64) + addr] = f2b(v);
                }
            }
        }
}

// ---------------- flash attention (round-14 best config, untouched) ----------
__global__ __launch_bounds__(256, 3) void k_attn4(
    const u16* __restrict__ qg, const u16* __restrict__ kg,
    const u16* __restrict__ vtg, u16* __restrict__ attnb)
{
    __shared__ float Ol[4][32][68];
    __shared__ float Ml[4][32];
    __shared__ float Ll[4][32];

    const int t = threadIdx.x;
    const int lane = t & 63, w = t >> 6;
    const int qc = lane & 31, hi = lane >> 5;
    const int bid = blockIdx.x;
    const int xcd = bid & 7, slot = bid >> 3;
    const int bh = xcd * 4 + (slot & 3);
    const int pr = slot >> 2;
    const int b = bh >> 4, h = bh & 15;
    const float slope2 = fexp2(-0.5f * (float)(h + 1)) * 1.44269504f;
    const float SC = 0.18033688f;
    const long base = (long)bh * (S_LEN * 64L);

    const u16* kptr = kg + base + lane * 8;
    const u16* vptr = vtg + base + lane * 8;
    const u16* qptr = qg + base + lane * 8;

#define LOADK(S, DST) {                                                   \
        const u16* kr_ = kptr + (long)(S) * 2048;                         \
        DST[0] = *reinterpret_cast<const bf16x8*>(kr_);                   \
        DST[1] = *reinterpret_cast<const bf16x8*>(kr_ + 512);             \
        DST[2] = *reinterpret_cast<const bf16x8*>(kr_ + 1024);            \
        DST[3] = *reinterpret_cast<const bf16x8*>(kr_ + 1536); }

    for (int pi = 0; pi < 2; ++pi) {
        const int qt = pi ? pr : 63 - pr;
        const int q_abs = qt * 32 + qc;

        bf16x8 qf[4];
        {
            const u16* qt_ = qptr + (long)qt * 2048;
#pragma unroll
            for (int ds = 0; ds < 4; ++ds)
                qf[ds] = *reinterpret_cast<const bf16x8*>(qt_ + ds * 512);
        }

        f32x16 oacc[2];
#pragma unroll
        for (int i = 0; i < 16; ++i) { oacc[0][i] = 0.f; oacc[1][i] = 0.f; }
        float m = -1e30f, l = 0.f;

        const int nsub = qt + 1;
        const int L = (nsub + 3) >> 2;
        const int s_beg = w * L;
        const int s_end = min(s_beg + L, nsub);
        const bool has_diag = (s_beg < s_end) && (s_end == nsub);
        const int e_un = has_diag ? s_end - 1 : s_end;

        bf16x8 kf[4];

        auto SUBTILE = [&](int s, int nxt, auto MASKC) {
            constexpr bool MASK = decltype(MASKC)::value;
            const int k0 = s * 32;
            f32x16 st;
#pragma unroll
            for (int i = 0; i < 16; ++i) st[i] = 0.f;
#pragma unroll
            for (int ds = 0; ds < 4; ++ds)
                st = __builtin_amdgcn_mfma_f32_32x32x16_bf16(kf[ds], qf[ds], st, 0, 0, 0);
            if (nxt >= 0) LOADK(nxt, kf);
            bf16x8 vf[2][2];
            {
                const u16* vt_ = vptr + (long)s * 2048;
#pragma unroll
                for (int dh = 0; dh < 2; ++dh)
#pragma unroll
                    for (int ks = 0; ks < 2; ++ks)
                        vf[dh][ks] = *reinterpret_cast<const bf16x8*>(
                            vt_ + dh * 1024 + ks * 512);
            }

            const float b0 = slope2 * (float)(k0 - q_abs + 4 * hi);
#pragma unroll
            for (int r = 0; r < 16; ++r) {
                const int roff = (r & 3) + 8 * (r >> 2);
                float xx = fmaf(st[r], SC, fmaf((float)roff, slope2, b0));
                if (MASK) {
                    const int kabs = k0 + roff + 4 * hi;
                    xx = (kabs > q_abs) ? -1e30f : xx;
                }
                st[r] = xx;
            }
            float mt[8];
#pragma unroll
            for (int r = 0; r < 8; ++r) mt[r] = fmaxf(st[2 * r], st[2 * r + 1]);
#pragma unroll
            for (int r = 0; r < 4; ++r) mt[r] = fmaxf(mt[r], mt[r + 4]);
            mt[0] = fmaxf(mt[0], mt[2]); mt[1] = fmaxf(mt[1], mt[3]);
            float mloc = xhalf_max(fmaxf(mt[0], mt[1]));

            if (!__all(mloc <= m + 11.5416f)) {
                const float mnew = fmaxf(m, mloc);
                const float corr = fexp2(m - mnew);
                m = mnew;
                l *= corr;
#pragma unroll
                for (int i = 0; i < 16; ++i) { oacc[0][i] *= corr; oacc[1][i] *= corr; }
            }

#pragma unroll
            for (int r = 0; r < 16; ++r) st[r] = fexp2(st[r] - m);
            float pt[8];
#pragma unroll
            for (int r = 0; r < 8; ++r) pt[r] = st[2 * r] + st[2 * r + 1];
#pragma unroll
            for (int r = 0; r < 4; ++r) pt[r] = pt[r] + pt[r + 4];
            pt[0] += pt[2]; pt[1] += pt[3];
            l += xhalf_add(pt[0] + pt[1]);

            bf16x8 pa[2];
#pragma unroll
            for (int g2 = 0; g2 < 2; ++g2) {
                uint32_t o0 = pk2(st[8 * g2 + 0], st[8 * g2 + 1]);
                uint32_t o1 = pk2(st[8 * g2 + 2], st[8 * g2 + 3]);
                uint32_t o2 = pk2(st[8 * g2 + 4], st[8 * g2 + 5]);
                uint32_t o3 = pk2(st[8 * g2 + 6], st[8 * g2 + 7]);
                uint2v ra = plswap(o0, o2);
                uint2v rb = plswap(o1, o3);
                union { uint32_t wd[4]; bf16x8 v; } c;
                c.wd[0] = ra[0]; c.wd[1] = rb[0]; c.wd[2] = ra[1]; c.wd[3] = rb[1];
                pa[g2] = c.v;
            }
#pragma unroll
            for (int ks = 0; ks < 2; ++ks)
#pragma unroll
                for (int dh = 0; dh < 2; ++dh)
                    oacc[dh] = __builtin_amdgcn_mfma_f32_32x32x16_bf16(vf[dh][ks], pa[ks], oacc[dh], 0, 0, 0);
        };

        int s = s_beg;
        if (s < s_end) LOADK(s, kf);
        for (; s < e_un; ++s)
            SUBTILE(s, (s + 1 < s_end) ? s + 1 : -1, FalseT{});
        if (has_diag)
            SUBTILE(qt, -1, TrueT{});

#pragma unroll
        for (int dh = 0; dh < 2; ++dh)
#pragma unroll
            for (int g = 0; g < 4; ++g) {
                float4 o4 = make_float4(oacc[dh][4 * g + 0], oacc[dh][4 * g + 1],
                                        oacc[dh][4 * g + 2], oacc[dh][4 * g + 3]);
                *reinterpret_cast<float4*>(&Ol[w][qc][dh * 32 + g * 8 + hi * 4]) = o4;
            }
        if (hi == 0) { Ml[w][qc] = m; Ll[w][qc] = l; }
        __syncthreads();

        {
            const int q = t >> 3, dg = t & 7;
            const float m0v = Ml[0][q], m1v = Ml[1][q], m2v = Ml[2][q], m3v = Ml[3][q];
            const float M = fmaxf(fmaxf(m0v, m1v), fmaxf(m2v, m3v));
            float wgt[4];
            wgt[0] = fexp2(m0v - M); wgt[1] = fexp2(m1v - M);
            wgt[2] = fexp2(m2v - M); wgt[3] = fexp2(m3v - M);
            const float lsum = wgt[0] * Ll[0][q] + wgt[1] * Ll[1][q] +
                               wgt[2] * Ll[2][q] + wgt[3] * Ll[3][q];
            float acc8[8];
#pragma unroll
            for (int e = 0; e < 8; ++e) acc8[e] = 0.f;
#pragma unroll
            for (int w4 = 0; w4 < 4; ++w4) {
                const float wg = wgt[w4];
#pragma unroll
                for (int e = 0; e < 8; ++e)
                    acc8[e] += wg * Ol[w4][q][dg * 8 + e];
            }
            const float inv = 1.0f / lsum;
            u16 ob[8];
#pragma unroll
            for (int e = 0; e < 8; ++e) ob[e] = f2b(acc8[e] * inv);
            *reinterpret_cast<uint4*>(
                &attnb[((long)b * S_LEN + qt * 32 + q) * 1024 + h * 64 + dg * 8]) =
                *reinterpret_cast<uint4*>(&ob[0]);
        }
        __syncthreads();
    }
#undef LOADK
}

// ---------------- LayerNorm over (P0+P1 f32 planes + resid + pbias) ---------
__global__ __launch_bounds__(256) void k_ln(
    const float* __restrict__ P0, const float* __restrict__ P1,
    const float* __restrict__ resid, const float* __restrict__ pbias,
    const float* __restrict__ g, const float* __restrict__ be,
    float* __restrict__ outf, u16* __restrict__ outb, int writeb)
{
    __shared__ float red[2][4];
    const int row = blockIdx.x, t = threadIdx.x;
    const long o = (long)row * 1024 + t * 4;
    float4 a0 = *reinterpret_cast<const float4*>(P0 + o);
    float4 a1 = *reinterpret_cast<const float4*>(P1 + o);
    float4 rr = *reinterpret_cast<const float4*>(resid + o);
    float4 pb = *reinterpret_cast<const float4*>(pbias + t * 4);
    float4 vv;
    vv.x = a0.x + a1.x + rr.x + pb.x;
    vv.y = a0.y + a1.y + rr.y + pb.y;
    vv.z = a0.z + a1.z + rr.z + pb.z;
    vv.w = a0.w + a1.w + rr.w + pb.w;
    float s = vv.x + vv.y + vv.z + vv.w;
    float sq = vv.x * vv.x + vv.y * vv.y + vv.z * vv.z + vv.w * vv.w;
#pragma unroll
    for (int off = 1; off < 64; off <<= 1) {
        s += __shfl_xor(s, off, 64);
        sq += __shfl_xor(sq, off, 64);
    }
    const int w = t >> 6;
    if ((t & 63) == 0) { red[0][w] = s; red[1][w] = sq; }
    __syncthreads();
    s = red[0][0] + red[0][1] + red[0][2] + red[0][3];
    sq = red[1][0] + red[1][1] + red[1][2] + red[1][3];
    const float mu = s * (1.f / 1024.f);
    const float var = sq * (1.f / 1024.f) - mu * mu;
    const float rs = rsqrtf(var + 1e-5f);
    float4 gv = *reinterpret_cast<const float4*>(&g[t * 4]);
    float4 bv = *reinterpret_cast<const float4*>(&be[t * 4]);
    float4 ov;
    ov.x = (vv.x - mu) * rs * gv.x + bv.x;
    ov.y = (vv.y - mu) * rs * gv.y + bv.y;
    ov.z = (vv.z - mu) * rs * gv.z + bv.z;
    ov.w = (vv.w - mu) * rs * gv.w + bv.w;
    *reinterpret_cast<float4*>(&outf[o]) = ov;
    if (writeb) {
        ushort4 ob;
        ob.x = f2b(ov.x); ob.y = f2b(ov.y); ob.z = f2b(ov.z); ob.w = f2b(ov.w);
        *reinterpret_cast<ushort4*>(&outb[o]) = ob;
    }
}

// ---------------- LayerNorm over (4 bf16 partial planes + resid + pbias) ----
__global__ __launch_bounds__(256) void k_ln4b(
    const u16* __restrict__ P, long plane,   // 4 planes at P + z*plane
    const float* __restrict__ resid, const float* __restrict__ pbias,
    const float* __restrict__ g, const float* __restrict__ be,
    float* __restrict__ outf)
{
    __shared__ float red[2][4];
    const int row = blockIdx.x, t = threadIdx.x;
    const long o = (long)row * 1024 + t * 4;
    float4 rr = *reinterpret_cast<const float4*>(resid + o);
    float4 pb = *reinterpret_cast<const float4*>(pbias + t * 4);
    float4 vv;
    vv.x = rr.x + pb.x; vv.y = rr.y + pb.y;
    vv.z = rr.z + pb.z; vv.w = rr.w + pb.w;
#pragma unroll
    for (int z = 0; z < 4; ++z) {
        ushort4 p4 = *reinterpret_cast<const ushort4*>(P + z * plane + o);
        vv.x += b2f(p4.x); vv.y += b2f(p4.y);
        vv.z += b2f(p4.z); vv.w += b2f(p4.w);
    }
    float s = vv.x + vv.y + vv.z + vv.w;
    float sq = vv.x * vv.x + vv.y * vv.y + vv.z * vv.z + vv.w * vv.w;
#pragma unroll
    for (int off = 1; off < 64; off <<= 1) {
        s += __shfl_xor(s, off, 64);
        sq += __shfl_xor(sq, off, 64);
    }
    const int w = t >> 6;
    if ((t & 63) == 0) { red[0][w] = s; red[1][w] = sq; }
    __syncthreads();
    s = red[0][0] + red[0][1] + red[0][2] + red[0][3];
    sq = red[1][0] + red[1][1] + red[1][2] + red[1][3];
    const float mu = s * (1.f / 1024.f);
    const float var = sq * (1.f / 1024.f) - mu * mu;
    const float rs = rsqrtf(var + 1e-5f);
    float4 gv = *reinterpret_cast<const float4*>(&g[t * 4]);
    float4 bv = *reinterpret_cast<const float4*>(&be[t * 4]);
    float4 ov;
    ov.x = (vv.x - mu) * rs * gv.x + bv.x;
    ov.y = (vv.y - mu) * rs * gv.y + bv.y;
    ov.z = (vv.z - mu) * rs * gv.z + bv.z;
    ov.w = (vv.w - mu) * rs * gv.w + bv.w;
    *reinterpret_cast<float4*>(&outf[o]) = ov;
}

extern "C" void kernel_launch(void* const* d_in, const int* in_sizes, int n_in,
                              void* d_out, int out_size, void* d_ws, size_t ws_size,
                              hipStream_t stream)
{
    const float* x  = (const float*)d_in[0];
    const float* Wq = (const float*)d_in[2];  const float* bq = (const float*)d_in[3];
    const float* Wk = (const float*)d_in[4];  const float* bk = (const float*)d_in[5];
    const float* Wv = (const float*)d_in[6];  const float* bv = (const float*)d_in[7];
    const float* Wo = (const float*)d_in[8];  const float* bo = (const float*)d_in[9];
    const float* W1 = (const float*)d_in[10]; const float* b1 = (const float*)d_in[11];
    const float* W2 = (const float*)d_in[12]; const float* b2 = (const float*)d_in[13];
    const float* g1 = (const float*)d_in[14]; const float* be1 = (const float*)d_in[15];
    const float* g2 = (const float*)d_in[16]; const float* be2 = (const float*)d_in[17];
    float* out = (float*)d_out;

    // ---- workspace layout (peak 104MB) ----
    char* ws = (char*)d_ws;
    const size_t MB = 1 << 20;
    u16* XB   = (u16*)(ws + 0 * MB);     // 8MB : convert -> QKV gemm
    u16* QKVT = (u16*)(ws + 8 * MB);     // 6MB
    u16* WOT  = (u16*)(ws + 14 * MB);    // 2MB
    u16* W1T  = (u16*)(ws + 16 * MB);    // 8MB (dead after FF1)
    u16* W2T  = (u16*)(ws + 96 * MB);    // 8MB (96-104)
    u16* QKV  = (u16*)(ws + 32 * MB);    // 24MB packed Q'/K'/V'
    u16* AT   = (u16*)(ws + 64 * MB);    // 8MB attn out
    float* OP = (float*)(ws + 32 * MB);  // 32MB out-proj f32 partials (over dead QKV)
    float* Y1 = (float*)(ws + 0 * MB);   // 16MB LN1 out f32 (over dead XB/QKVT/WOT)
    u16* Y1B  = (u16*)(ws + 64 * MB);    // 8MB LN1 out bf16 (over dead AT)
    u16* Hb   = (u16*)(ws + 24 * MB);    // 32MB FF1 out (over dead OP tail/QKV)
    u16* FPB  = (u16*)(ws + 56 * MB);    // 32MB FF2 bf16 partials x4 (56-88)

    u16* Qb = QKV;
    u16* Kb = QKV + 32L * 2048 * 64;
    u16* Vb = QKV + 2 * 32L * 2048 * 64;

    dim3 blk(256);

    k_convert_bf16<<<dim3(4096), blk, 0, stream>>>(x, XB, 4096 * 1024);
    k_transpose_w<<<dim3(32, 32), blk, 0, stream>>>(Wq, QKVT, 1024, 1024);
    k_transpose_w<<<dim3(32, 32), blk, 0, stream>>>(Wk, QKVT + 1024L * 1024, 1024, 1024);
    k_transpose_w<<<dim3(32, 32), blk, 0, stream>>>(Wv, QKVT + 2048L * 1024, 1024, 1024);
    k_transpose_w<<<dim3(32, 32), blk, 0, stream>>>(Wo, WOT, 1024, 1024);
    k_transpose_w<<<dim3(128, 32), blk, 0, stream>>>(W1, W1T, 1024, 4096);
    k_transpose_w<<<dim3(32, 128), blk, 0, stream>>>(W2, W2T, 4096, 1024);

    // fused QKV projection: 256x128 counted-vmcnt, grid (24,16) = 384 blocks,
    // patch (2,4): hb=8, wb=6, va*vb=8. Packed Q'/K'/V' scatter epilogue.
    k_gemm8n<1><<<dim3(24, 16), dim3(512), 0, stream>>>(
        XB, QKVT, bq, bk, bv, QKV, nullptr, 4096, 3072, 1024, 2, 4);

    k_attn4<<<dim3(1024), blk, 0, stream>>>(Qb, Kb, Vb, AT);

    // attn out-proj: 256x128 counted-vmcnt, split-K=2, patch (2,4) -> LN1
    k_gemm8n<0><<<dim3(8, 16, 2), dim3(512), 0, stream>>>(
        AT, WOT, nullptr, nullptr, nullptr, nullptr, OP, 4096, 1024, 1024, 2, 4);
    k_ln<<<dim3(4096), blk, 0, stream>>>(OP, OP + 4096L * 1024, x, bo,
                                         g1, be1, Y1, Y1B, 1);
    // FF1: 256x256 counted-vmcnt 4-phase, grid 16x16 (1/CU), patch (2,4)
    k_gemm8<0><<<dim3(16, 16), dim3(512), 0, stream>>>(Y1B, W1T, b1, Hb,
                                                       4096, 4096, 1024, 2, 4);
    // FF2: 256x256 counted-vmcnt 4-phase, split-K=4 (grid 4x16x4 = 256 = 1/CU),
    // bf16 partial planes -> k_ln4b. patch (4,2).
    k_gemm8<1><<<dim3(4, 16, 4), dim3(512), 0, stream>>>(Hb, W2T, nullptr, FPB,
                                                         4096, 1024, 4096, 4, 2);
    k_ln4b<<<dim3(4096), blk, 0, stream>>>(FPB, 4096L * 1024, Y1, b2,
                                           g2, be2, out);
}

// Round 23
// 220.085 us; speedup vs baseline: 1.0513x; 1.0513x over previous
//
#include <hip/hip_runtime.h>
#include <stdint.h>

typedef unsigned short u16;
typedef __bf16 bf16x8 __attribute__((ext_vector_type(8)));
typedef float f32x4 __attribute__((ext_vector_type(4)));
typedef float f32x16 __attribute__((ext_vector_type(16)));
typedef unsigned int uint2v __attribute__((ext_vector_type(2)));

#define S_LEN 2048
#define D_MODEL 1024

struct TrueT  { static constexpr bool value = true;  };
struct FalseT { static constexpr bool value = false; };

__device__ __forceinline__ u16 f2b(float f) {
    uint32_t u = __float_as_uint(f);
    u += 0x7FFFu + ((u >> 16) & 1u);   // round-to-nearest-even
    return (u16)(u >> 16);
}

__device__ __forceinline__ float b2f(u16 b) {
    uint32_t u = (uint32_t)b << 16;
    return __uint_as_float(u);
}

__device__ __forceinline__ uint32_t pk2(float a, float b) {
    union { struct { __bf16 l, h; } s; uint32_t u; } c;
    c.s.l = (__bf16)a; c.s.h = (__bf16)b; return c.u;
}

__device__ __forceinline__ float fexp2(float x) {
#if __has_builtin(__builtin_amdgcn_exp2f)
    return __builtin_amdgcn_exp2f(x);
#else
    return exp2f(x);
#endif
}

// permlane32_swap(a,b) -> {new_a, new_b}
__device__ __forceinline__ uint2v plswap(uint32_t a, uint32_t b) {
#if __has_builtin(__builtin_amdgcn_permlane32_swap)
    return __builtin_amdgcn_permlane32_swap(a, b, false, false);
#else
    uint2v r;
    uint32_t pa = (uint32_t)__shfl_xor((int)a, 32, 64);
    uint32_t pb = (uint32_t)__shfl_xor((int)b, 32, 64);
    const int hi = (threadIdx.x & 63) >> 5;
    r[0] = hi ? pb : a;
    r[1] = hi ? b : pa;
    return r;
#endif
}
__device__ __forceinline__ float xhalf_max(float x) {
    uint2v r = plswap(__float_as_uint(x), __float_as_uint(x));
    return fmaxf(__uint_as_float(r[0]), __uint_as_float(r[1]));
}
__device__ __forceinline__ float xhalf_add(float x) {
    uint2v r = plswap(__float_as_uint(x), __float_as_uint(x));
    return __uint_as_float(r[0]) + __uint_as_float(r[1]);
}

__device__ __forceinline__ void gl16(const void* g, void* l) {
    __builtin_amdgcn_global_load_lds(
        (const __attribute__((address_space(1))) void*)g,
        (__attribute__((address_space(3))) void*)l, 16, 0, 0);
}

// ---------------- elementwise f32 -> bf16 ----------------
__global__ __launch_bounds__(256) void k_convert_bf16(
    const float* __restrict__ in, u16* __restrict__ out, int n)
{
    int i = (blockIdx.x * 256 + threadIdx.x) * 4;
    if (i >= n) return;
    float4 v = *reinterpret_cast<const float4*>(in + i);
    ushort4 o;
    o.x = f2b(v.x); o.y = f2b(v.y); o.z = f2b(v.z); o.w = f2b(v.w);
    *reinterpret_cast<ushort4*>(out + i) = o;
}

// ---------------- W [K,N] f32 -> WT [N,K] bf16 ----------------
__global__ __launch_bounds__(256) void k_transpose_w(
    const float* __restrict__ W, u16* __restrict__ WT, int K, int N)
{
    __shared__ float tile[32][33];
    const int nt = blockIdx.x, kt = blockIdx.y;
    const int tx = threadIdx.x & 31, ty = threadIdx.x >> 5;  // ty 0..7
#pragma unroll
    for (int i = 0; i < 4; ++i)
        tile[ty + i * 8][tx] = W[(long)(kt * 32 + ty + i * 8) * N + nt * 32 + tx];
    __syncthreads();
#pragma unroll
    for (int i = 0; i < 4; ++i)
        WT[(long)(nt * 32 + ty + i * 8) * K + kt * 32 + tx] = f2b(tile[tx][ty + i * 8]);
}

// ---------------- GEMM (2-phase 128x128, proven path: QKV only) ----------------
// MODE 0: out bf16 scattered to PACKED Q'/K'/V' fragment layouts.
// QKV structural ledger (rounds 19-22, measured): 2ph-128^2 @3/CU = 46us BEST;
// 4ph-256^2 @192blk = 50us; counted-2ph 256x128 @384blk(1.5 rounds) = 58.5us.
// For M=4096,N=3072,K=1024 TLP at 3 blocks/CU beats deeper per-block pipelining.
template <int MODE>
__global__ __launch_bounds__(256) void k_gemm(
    const u16* __restrict__ A, const u16* __restrict__ BT,
    const float* __restrict__ bias, const float* __restrict__ bias2,
    const float* __restrict__ bias3,
    u16* __restrict__ outb, float* __restrict__ outf,
    int M, int N, int K, int va, int vb)
{
    __shared__ u16 As[2][128 * 32];
    __shared__ u16 Bs[2][128 * 32];
    const int t = threadIdx.x;
    const int lane = t & 63, wid = t >> 6;
    const int wm = wid >> 1, wn = wid & 1;
    const int lr = lane & 15, lg = lane >> 4;

    const int GX = gridDim.x, GY = gridDim.y;
    const int dd = blockIdx.y * GX + blockIdx.x;
    const int xcd = dd & 7, ii = dd >> 3;
    const int hb = GY / va, wb = GX / vb;
    const int pr = xcd / vb, pc = xcd % vb;
    const int by = pr * hb + ii / wb;
    const int bx = pc * wb + ii % wb;
    const int m0 = by * 128, n0 = bx * 128;

    const int Kc = K / (int)gridDim.z;
    const long koff = (long)blockIdx.z * Kc;

    f32x4 acc[4][4];
#pragma unroll
    for (int i = 0; i < 4; ++i)
#pragma unroll
        for (int j = 0; j < 4; ++j) acc[i][j] = (f32x4){0.f, 0.f, 0.f, 0.f};

    const int r0 = t >> 2;
    const int ce = (t & 3) * 8;
    const u16* pA0 = A + (long)(m0 + r0) * K + ce + koff;
    const u16* pA1 = A + (long)(m0 + r0 + 64) * K + ce + koff;
    const u16* pB0 = BT + (long)(n0 + r0) * K + ce + koff;
    const u16* pB1 = BT + (long)(n0 + r0 + 64) * K + ce + koff;

    auto STAGE = [&](int buf, int k0) {
        u16* aw = &As[buf][wid * 512];
        u16* bw = &Bs[buf][wid * 512];
        gl16(pA0 + k0, aw);
        gl16(pA1 + k0, aw + 2048);
        gl16(pB0 + k0, bw);
        gl16(pB1 + k0, bw + 2048);
    };

    STAGE(0, 0);
    __syncthreads();
    int cur = 0;
    for (int k0 = 0; k0 < Kc; k0 += 32) {
        if (k0 + 32 < Kc) STAGE(cur ^ 1, k0 + 32);
        bf16x8 af[4], bfr[4];
#pragma unroll
        for (int i = 0; i < 4; ++i)
            af[i] = *reinterpret_cast<const bf16x8*>(&As[cur][(wm * 64 + i * 16 + lr) * 32 + lg * 8]);
#pragma unroll
        for (int j = 0; j < 4; ++j)
            bfr[j] = *reinterpret_cast<const bf16x8*>(&Bs[cur][(wn * 64 + j * 16 + lr) * 32 + lg * 8]);
#pragma unroll
        for (int i = 0; i < 4; ++i)
#pragma unroll
            for (int j = 0; j < 4; ++j)
                acc[i][j] = __builtin_amdgcn_mfma_f32_16x16x32_bf16(af[i], bfr[j], acc[i][j], 0, 0, 0);
        __syncthreads();
        cur ^= 1;
    }

    const long zoff = (long)blockIdx.z * M * N;
#pragma unroll
    for (int i = 0; i < 4; ++i) {
#pragma unroll
        for (int j = 0; j < 4; ++j) {
            const int n = n0 + wn * 64 + j * 16 + lr;
            float bn = 0.f;
            if (MODE == 0)
                bn = (n < 1024) ? bias[n] : (n < 2048) ? bias2[n - 1024] : bias3[n - 2048];
            else if (MODE == 2)
                bn = bias[n];
#pragma unroll
            for (int r = 0; r < 4; ++r) {
                const int m = m0 + wm * 64 + i * 16 + lg * 4 + r;
                float v = acc[i][j][r] + bn;
                if (MODE == 0) {
                    const int b = m >> 11, s = m & 2047;
                    const int which = n >> 10, nn = n & 1023;
                    const int h = nn >> 6, dk = nn & 63;
                    const long bhb = (long)(b * 16 + h) * (2048L * 64);
                    const int s32 = s >> 5, sr = s & 31;
                    long addr;
                    if (which < 2) {
                        addr = bhb + (long)s32 * 2048 + (dk >> 4) * 512 +
                               ((dk >> 3) & 1) * 256 + sr * 8 + (dk & 7);
                    } else {
                        addr = bhb + (long)s32 * 2048 + (dk >> 5) * 1024 +
                               ((sr >> 4) & 1) * 512 + ((sr >> 3) & 1) * 256 +
                               (dk & 31) * 8 + (sr & 7);
                    }
                    outb[(long)which * (32L * 2048 * 64) + addr] = f2b(v);
                } else if (MODE == 2) {
                    outb[(long)m * N + n] = f2b(fmaxf(v, 0.f));
                } else {
                    outf[zoff + (long)m * N + n] = v;
                }
            }
        }
    }
}

// ---------------- GEMM 256x256, BK=64, counted-vmcnt 4-phase ----------------
// MODE 0 (FF1): out bf16 = relu(val + bias), no split-K.
// MODE 1 (FF2): out bf16 PARTIAL plane z (no bias; k_ln4b folds 4 planes).
// PATCH INVARIANT: va*vb MUST be 8 (xcd 0..7 -> patch (xcd/vb, xcd%vb)).
// Swizzle: f(row) = (row>>1)&3 (full period-8 slot permutation, 0 conflicts).
template <int MODE>
__global__ __launch_bounds__(512, 2) void k_gemm8(
    const u16* __restrict__ A, const u16* __restrict__ BT,
    const float* __restrict__ bias, u16* __restrict__ outb,
    int M, int N, int K, int va, int vb)
{
    __shared__ u16 As[2][2][8192];   // [slot][khalf][256*32]
    __shared__ u16 Bs[2][2][8192];
    const int t = threadIdx.x;
    const int lane = t & 63, wid = t >> 6;      // 8 waves
    const int wm = wid >> 2, wn = wid & 3;
    const int lr = lane & 15, lg = lane >> 4;

    const int GX = gridDim.x, GY = gridDim.y;
    const int dd = blockIdx.y * GX + blockIdx.x;
    const int xcd = dd & 7, ii = dd >> 3;
    const int hb = GY / va, wb = GX / vb;
    const int by = (xcd / vb) * hb + ii / wb;
    const int bx = (xcd % vb) * wb + ii % wb;
    const int m0 = by * 256, n0 = bx * 256;

    const int Kc = K / (int)gridDim.z;
    const long koff = (long)blockIdx.z * Kc;
    const int NT = Kc >> 6;

    auto STAGEU = [&](const u16* __restrict__ P, int rbase, u16* lds_unit,
                      int tt, int kh) {
        const int ko = tt * 64 + kh * 32;
#pragma unroll
        for (int s = 0; s < 2; ++s) {
            const int c = wid * 64 + lane + s * 512;
            const int op = c * 16;
            const int row = op >> 6;
            const int kg = ((op >> 4) & 3) ^ ((row >> 1) & 3);
            gl16(P + (long)(rbase + row) * K + koff + ko + kg * 8,
                 (char*)lds_unit + op);
        }
    };
    auto RD = [&](const u16* unit, int rb) -> bf16x8 {
        const int row = rb + lr;
        const int op = (row * 64 + lg * 16) ^ (((row >> 1) & 3) << 4);
        return *reinterpret_cast<const bf16x8*>((const char*)unit + op);
    };

    f32x4 acc[8][4];
#pragma unroll
    for (int i = 0; i < 8; ++i)
#pragma unroll
        for (int j = 0; j < 4; ++j) acc[i][j] = (f32x4){0.f, 0.f, 0.f, 0.f};

    STAGEU(A, m0, &As[0][0][0], 0, 0);
    STAGEU(BT, n0, &Bs[0][0][0], 0, 0);
    STAGEU(A, m0, &As[0][1][0], 0, 1);
    STAGEU(BT, n0, &Bs[0][1][0], 0, 1);
    STAGEU(A, m0, &As[1][0][0], 1, 0);
    STAGEU(BT, n0, &Bs[1][0][0], 1, 0);
    asm volatile("s_waitcnt vmcnt(0)" ::: "memory");
    __builtin_amdgcn_s_barrier();

    for (int tt = 0; tt < NT; ++tt) {
        const int sl = tt & 1;
        bf16x8 af[4], bfr[4];

        // ---- phase 0: kh0, row-half 0 ----
#pragma unroll
        for (int rf = 0; rf < 4; ++rf)
            af[rf] = RD(&As[sl][0][0], wm * 128 + rf * 16);
#pragma unroll
        for (int cf = 0; cf < 4; ++cf)
            bfr[cf] = RD(&Bs[sl][0][0], wn * 64 + cf * 16);
        if (tt + 1 < NT) STAGEU(A, m0, &As[sl ^ 1][1][0], tt + 1, 1);
        __builtin_amdgcn_s_setprio(1);
#pragma unroll
        for (int cf = 0; cf < 4; ++cf)
#pragma unroll
            for (int rf = 0; rf < 4; ++rf)
                acc[rf][cf] = __builtin_amdgcn_mfma_f32_16x16x32_bf16(af[rf], bfr[cf], acc[rf][cf], 0, 0, 0);
        __builtin_amdgcn_s_setprio(0);
        __builtin_amdgcn_s_barrier();

        // ---- phase 1: kh0, row-half 1 ----
#pragma unroll
        for (int rf = 0; rf < 4; ++rf)
            af[rf] = RD(&As[sl][0][0], wm * 128 + 64 + rf * 16);
        if (tt + 1 < NT) STAGEU(BT, n0, &Bs[sl ^ 1][1][0], tt + 1, 1);
        __builtin_amdgcn_s_setprio(1);
#pragma unroll
        for (int cf = 0; cf < 4; ++cf)
#pragma unroll
            for (int rf = 0; rf < 4; ++rf)
                acc[4 + rf][cf] = __builtin_amdgcn_mfma_f32_16x16x32_bf16(af[rf], bfr[cf], acc[4 + rf][cf], 0, 0, 0);
        __builtin_amdgcn_s_setprio(0);
        asm volatile("s_waitcnt vmcnt(8)" ::: "memory");
        __builtin_amdgcn_s_barrier();

        // ---- phase 2: kh1, row-half 0 ----
#pragma unroll
        for (int rf = 0; rf < 4; ++rf)
            af[rf] = RD(&As[sl][1][0], wm * 128 + rf * 16);
#pragma unroll
        for (int cf = 0; cf < 4; ++cf)
            bfr[cf] = RD(&Bs[sl][1][0], wn * 64 + cf * 16);
        if (tt + 2 < NT) STAGEU(A, m0, &As[sl][0][0], tt + 2, 0);
        __builtin_amdgcn_s_setprio(1);
#pragma unroll
        for (int cf = 0; cf < 4; ++cf)
#pragma unroll
            for (int rf = 0; rf < 4; ++rf)
                acc[rf][cf] = __builtin_amdgcn_mfma_f32_16x16x32_bf16(af[rf], bfr[cf], acc[rf][cf], 0, 0, 0);
        __builtin_amdgcn_s_setprio(0);
        __builtin_amdgcn_s_barrier();

        // ---- phase 3: kh1, row-half 1 ----
#pragma unroll
        for (int rf = 0; rf < 4; ++rf)
            af[rf] = RD(&As[sl][1][0], wm * 128 + 64 + rf * 16);
        if (tt + 2 < NT) STAGEU(BT, n0, &Bs[sl][0][0], tt + 2, 0);
        __builtin_amdgcn_s_setprio(1);
#pragma unroll
        for (int cf = 0; cf < 4; ++cf)
#pragma unroll
            for (int rf = 0; rf < 4; ++rf)
                acc[4 + rf][cf] = __builtin_amdgcn_mfma_f32_16x16x32_bf16(af[rf], bfr[cf], acc[4 + rf][cf], 0, 0, 0);
        __builtin_amdgcn_s_setprio(0);
        asm volatile("s_waitcnt vmcnt(8)" ::: "memory");
        __builtin_amdgcn_s_barrier();
    }

    // epilogue
    const long zoff = (long)blockIdx.z * M * N;
#pragma unroll
    for (int fr = 0; fr < 8; ++fr)
#pragma unroll
        for (int cf = 0; cf < 4; ++cf) {
            const int n = n0 + wn * 64 + cf * 16 + lr;
            const float bn = (MODE == 0) ? bias[n] : 0.f;
#pragma unroll
            for (int r = 0; r < 4; ++r) {
                const int m = m0 + wm * 128 + fr * 16 + lg * 4 + r;
                if (MODE == 0)
                    outb[(long)m * N + n] = f2b(fmaxf(acc[fr][cf][r] + bn, 0.f));
                else
                    outb[zoff + (long)m * N + n] = f2b(acc[fr][cf][r]);
            }
        }
}

// ---------------- GEMM 256x128, BK=64, counted-vmcnt 2-phase (OP) ------
// Output: f32 partial plane z (consumer LN folds bias/resid/partials).
__global__ __launch_bounds__(512, 2) void k_gemm8n(
    const u16* __restrict__ A, const u16* __restrict__ BT,
    float* __restrict__ outf, int M, int N, int K, int va, int vb)
{
    __shared__ u16 As[2][2][8192];   // [slot][khalf][256 rows * 32 k]
    __shared__ u16 Bs[2][2][4096];   // [slot][khalf][128 rows * 32 k]
    const int t = threadIdx.x;
    const int lane = t & 63, wid = t >> 6;      // 8 waves, 4M x 2N
    const int wm = wid >> 1, wn = wid & 1;
    const int lr = lane & 15, lg = lane >> 4;

    const int GX = gridDim.x, GY = gridDim.y;
    const int dd = blockIdx.y * GX + blockIdx.x;
    const int xcd = dd & 7, ii = dd >> 3;
    const int hb = GY / va, wb = GX / vb;
    const int by = (xcd / vb) * hb + ii / wb;
    const int bx = (xcd % vb) * wb + ii % wb;
    const int m0 = by * 256, n0 = bx * 128;

    const int Kc = K / (int)gridDim.z;
    const long koff = (long)blockIdx.z * Kc;
    const int NT = Kc >> 6;

    auto STAGEA = [&](u16* lds_unit, int tt, int kh) {
        const int ko = tt * 64 + kh * 32;
#pragma unroll
        for (int s = 0; s < 2; ++s) {
            const int c = wid * 64 + lane + s * 512;
            const int op = c * 16;
            const int row = op >> 6;
            const int kg = ((op >> 4) & 3) ^ ((row >> 1) & 3);
            gl16(A + (long)(m0 + row) * K + koff + ko + kg * 8,
                 (char*)lds_unit + op);
        }
    };
    auto STAGEB = [&](u16* lds_unit, int tt, int kh) {
        const int ko = tt * 64 + kh * 32;
        const int c = wid * 64 + lane;
        const int op = c * 16;
        const int row = op >> 6;
        const int kg = ((op >> 4) & 3) ^ ((row >> 1) & 3);
        gl16(BT + (long)(n0 + row) * K + koff + ko + kg * 8,
             (char*)lds_unit + op);
    };
    auto RD = [&](const u16* unit, int rb) -> bf16x8 {
        const int row = rb + lr;
        const int op = (row * 64 + lg * 16) ^ (((row >> 1) & 3) << 4);
        return *reinterpret_cast<const bf16x8*>((const char*)unit + op);
    };

    f32x4 acc[4][4];
#pragma unroll
    for (int i = 0; i < 4; ++i)
#pragma unroll
        for (int j = 0; j < 4; ++j) acc[i][j] = (f32x4){0.f, 0.f, 0.f, 0.f};

    STAGEA(&As[0][0][0], 0, 0); STAGEB(&Bs[0][0][0], 0, 0);
    STAGEA(&As[0][1][0], 0, 1); STAGEB(&Bs[0][1][0], 0, 1);
    STAGEA(&As[1][0][0], 1, 0); STAGEB(&Bs[1][0][0], 1, 0);
    asm volatile("s_waitcnt vmcnt(0)" ::: "memory");
    __builtin_amdgcn_s_barrier();

    for (int tt = 0; tt < NT; ++tt) {
        const int sl = tt & 1;
        bf16x8 af[4], bfr[4];

#pragma unroll
        for (int rf = 0; rf < 4; ++rf)
            af[rf] = RD(&As[sl][0][0], wm * 64 + rf * 16);
#pragma unroll
        for (int cf = 0; cf < 4; ++cf)
            bfr[cf] = RD(&Bs[sl][0][0], wn * 64 + cf * 16);
        if (tt + 1 < NT) {
            STAGEA(&As[sl ^ 1][1][0], tt + 1, 1);
            STAGEB(&Bs[sl ^ 1][1][0], tt + 1, 1);
        }
        __builtin_amdgcn_s_setprio(1);
#pragma unroll
        for (int cf = 0; cf < 4; ++cf)
#pragma unroll
            for (int rf = 0; rf < 4; ++rf)
                acc[rf][cf] = __builtin_amdgcn_mfma_f32_16x16x32_bf16(af[rf], bfr[cf], acc[rf][cf], 0, 0, 0);
        __builtin_amdgcn_s_setprio(0);
        asm volatile("s_waitcnt vmcnt(6)" ::: "memory");
        __builtin_amdgcn_s_barrier();

#pragma unroll
        for (int rf = 0; rf < 4; ++rf)
            af[rf] = RD(&As[sl][1][0], wm * 64 + rf * 16);
#pragma unroll
        for (int cf = 0; cf < 4; ++cf)
            bfr[cf] = RD(&Bs[sl][1][0], wn * 64 + cf * 16);
        if (tt + 2 < NT) {
            STAGEA(&As[sl][0][0], tt + 2, 0);
            STAGEB(&Bs[sl][0][0], tt + 2, 0);
        }
        __builtin_amdgcn_s_setprio(1);
#pragma unroll
        for (int cf = 0; cf < 4; ++cf)
#pragma unroll
            for (int rf = 0; rf < 4; ++rf)
                acc[rf][cf] = __builtin_amdgcn_mfma_f32_16x16x32_bf16(af[rf], bfr[cf], acc[rf][cf], 0, 0, 0);
        __builtin_amdgcn_s_setprio(0);
        asm volatile("s_waitcnt vmcnt(6)" ::: "memory");
        __builtin_amdgcn_s_barrier();
    }

    const long zoff = (long)blockIdx.z * M * N;
#pragma unroll
    for (int fr = 0; fr < 4; ++fr)
#pragma unroll
        for (int cf = 0; cf < 4; ++cf) {
            const int n = n0 + wn * 64 + cf * 16 + lr;
#pragma unroll
            for (int r = 0; r < 4; ++r) {
                const int m = m0 + wm * 64 + fr * 16 + lg * 4 + r;
                outf[zoff + (long)m * N + n] = acc[fr][cf][r];
            }
        }
}

// ---------------- flash attention (round-14 best config, untouched) ----------
__global__ __launch_bounds__(256, 3) void k_attn4(
    const u16* __restrict__ qg, const u16* __restrict__ kg,
    const u16* __restrict__ vtg, u16* __restrict__ attnb)
{
    __shared__ float Ol[4][32][68];
    __shared__ float Ml[4][32];
    __shared__ float Ll[4][32];

    const int t = threadIdx.x;
    const int lane = t & 63, w = t >> 6;
    const int qc = lane & 31, hi = lane >> 5;
    const int bid = blockIdx.x;
    const int xcd = bid & 7, slot = bid >> 3;
    const int bh = xcd * 4 + (slot & 3);
    const int pr = slot >> 2;
    const int b = bh >> 4, h = bh & 15;
    const float slope2 = fexp2(-0.5f * (float)(h + 1)) * 1.44269504f;
    const float SC = 0.18033688f;
    const long base = (long)bh * (S_LEN * 64L);

    const u16* kptr = kg + base + lane * 8;
    const u16* vptr = vtg + base + lane * 8;
    const u16* qptr = qg + base + lane * 8;

#define LOADK(S, DST) {                                                   \
        const u16* kr_ = kptr + (long)(S) * 2048;                         \
        DST[0] = *reinterpret_cast<const bf16x8*>(kr_);                   \
        DST[1] = *reinterpret_cast<const bf16x8*>(kr_ + 512);             \
        DST[2] = *reinterpret_cast<const bf16x8*>(kr_ + 1024);            \
        DST[3] = *reinterpret_cast<const bf16x8*>(kr_ + 1536); }

    for (int pi = 0; pi < 2; ++pi) {
        const int qt = pi ? pr : 63 - pr;
        const int q_abs = qt * 32 + qc;

        bf16x8 qf[4];
        {
            const u16* qt_ = qptr + (long)qt * 2048;
#pragma unroll
            for (int ds = 0; ds < 4; ++ds)
                qf[ds] = *reinterpret_cast<const bf16x8*>(qt_ + ds * 512);
        }

        f32x16 oacc[2];
#pragma unroll
        for (int i = 0; i < 16; ++i) { oacc[0][i] = 0.f; oacc[1][i] = 0.f; }
        float m = -1e30f, l = 0.f;

        const int nsub = qt + 1;
        const int L = (nsub + 3) >> 2;
        const int s_beg = w * L;
        const int s_end = min(s_beg + L, nsub);
        const bool has_diag = (s_beg < s_end) && (s_end == nsub);
        const int e_un = has_diag ? s_end - 1 : s_end;

        bf16x8 kf[4];

        auto SUBTILE = [&](int s, int nxt, auto MASKC) {
            constexpr bool MASK = decltype(MASKC)::value;
            const int k0 = s * 32;
            f32x16 st;
#pragma unroll
            for (int i = 0; i < 16; ++i) st[i] = 0.f;
#pragma unroll
            for (int ds = 0; ds < 4; ++ds)
                st = __builtin_amdgcn_mfma_f32_32x32x16_bf16(kf[ds], qf[ds], st, 0, 0, 0);
            if (nxt >= 0) LOADK(nxt, kf);
            bf16x8 vf[2][2];
            {
                const u16* vt_ = vptr + (long)s * 2048;
#pragma unroll
                for (int dh = 0; dh < 2; ++dh)
#pragma unroll
                    for (int ks = 0; ks < 2; ++ks)
                        vf[dh][ks] = *reinterpret_cast<const bf16x8*>(
                            vt_ + dh * 1024 + ks * 512);
            }

            const float b0 = slope2 * (float)(k0 - q_abs + 4 * hi);
#pragma unroll
            for (int r = 0; r < 16; ++r) {
                const int roff = (r & 3) + 8 * (r >> 2);
                float xx = fmaf(st[r], SC, fmaf((float)roff, slope2, b0));
                if (MASK) {
                    const int kabs = k0 + roff + 4 * hi;
                    xx = (kabs > q_abs) ? -1e30f : xx;
                }
                st[r] = xx;
            }
            float mt[8];
#pragma unroll
            for (int r = 0; r < 8; ++r) mt[r] = fmaxf(st[2 * r], st[2 * r + 1]);
#pragma unroll
            for (int r = 0; r < 4; ++r) mt[r] = fmaxf(mt[r], mt[r + 4]);
            mt[0] = fmaxf(mt[0], mt[2]); mt[1] = fmaxf(mt[1], mt[3]);
            float mloc = xhalf_max(fmaxf(mt[0], mt[1]));

            if (!__all(mloc <= m + 11.5416f)) {
                const float mnew = fmaxf(m, mloc);
                const float corr = fexp2(m - mnew);
                m = mnew;
                l *= corr;
#pragma unroll
                for (int i = 0; i < 16; ++i) { oacc[0][i] *= corr; oacc[1][i] *= corr; }
            }

#pragma unroll
            for (int r = 0; r < 16; ++r) st[r] = fexp2(st[r] - m);
            float pt[8];
#pragma unroll
            for (int r = 0; r < 8; ++r) pt[r] = st[2 * r] + st[2 * r + 1];
#pragma unroll
            for (int r = 0; r < 4; ++r) pt[r] = pt[r] + pt[r + 4];
            pt[0] += pt[2]; pt[1] += pt[3];
            l += xhalf_add(pt[0] + pt[1]);

            bf16x8 pa[2];
#pragma unroll
            for (int g2 = 0; g2 < 2; ++g2) {
                uint32_t o0 = pk2(st[8 * g2 + 0], st[8 * g2 + 1]);
                uint32_t o1 = pk2(st[8 * g2 + 2], st[8 * g2 + 3]);
                uint32_t o2 = pk2(st[8 * g2 + 4], st[8 * g2 + 5]);
                uint32_t o3 = pk2(st[8 * g2 + 6], st[8 * g2 + 7]);
                uint2v ra = plswap(o0, o2);
                uint2v rb = plswap(o1, o3);
                union { uint32_t wd[4]; bf16x8 v; } c;
                c.wd[0] = ra[0]; c.wd[1] = rb[0]; c.wd[2] = ra[1]; c.wd[3] = rb[1];
                pa[g2] = c.v;
            }
#pragma unroll
            for (int ks = 0; ks < 2; ++ks)
#pragma unroll
                for (int dh = 0; dh < 2; ++dh)
                    oacc[dh] = __builtin_amdgcn_mfma_f32_32x32x16_bf16(vf[dh][ks], pa[ks], oacc[dh], 0, 0, 0);
        };

        int s = s_beg;
        if (s < s_end) LOADK(s, kf);
        for (; s < e_un; ++s)
            SUBTILE(s, (s + 1 < s_end) ? s + 1 : -1, FalseT{});
        if (has_diag)
            SUBTILE(qt, -1, TrueT{});

#pragma unroll
        for (int dh = 0; dh < 2; ++dh)
#pragma unroll
            for (int g = 0; g < 4; ++g) {
                float4 o4 = make_float4(oacc[dh][4 * g + 0], oacc[dh][4 * g + 1],
                                        oacc[dh][4 * g + 2], oacc[dh][4 * g + 3]);
                *reinterpret_cast<float4*>(&Ol[w][qc][dh * 32 + g * 8 + hi * 4]) = o4;
            }
        if (hi == 0) { Ml[w][qc] = m; Ll[w][qc] = l; }
        __syncthreads();

        {
            const int q = t >> 3, dg = t & 7;
            const float m0v = Ml[0][q], m1v = Ml[1][q], m2v = Ml[2][q], m3v = Ml[3][q];
            const float M = fmaxf(fmaxf(m0v, m1v), fmaxf(m2v, m3v));
            float wgt[4];
            wgt[0] = fexp2(m0v - M); wgt[1] = fexp2(m1v - M);
            wgt[2] = fexp2(m2v - M); wgt[3] = fexp2(m3v - M);
            const float lsum = wgt[0] * Ll[0][q] + wgt[1] * Ll[1][q] +
                               wgt[2] * Ll[2][q] + wgt[3] * Ll[3][q];
            float acc8[8];
#pragma unroll
            for (int e = 0; e < 8; ++e) acc8[e] = 0.f;
#pragma unroll
            for (int w4 = 0; w4 < 4; ++w4) {
                const float wg = wgt[w4];
#pragma unroll
                for (int e = 0; e < 8; ++e)
                    acc8[e] += wg * Ol[w4][q][dg * 8 + e];
            }
            const float inv = 1.0f / lsum;
            u16 ob[8];
#pragma unroll
            for (int e = 0; e < 8; ++e) ob[e] = f2b(acc8[e] * inv);
            *reinterpret_cast<uint4*>(
                &attnb[((long)b * S_LEN + qt * 32 + q) * 1024 + h * 64 + dg * 8]) =
                *reinterpret_cast<uint4*>(&ob[0]);
        }
        __syncthreads();
    }
#undef LOADK
}

// ---------------- LayerNorm over (P0+P1 f32 planes + resid + pbias) ---------
__global__ __launch_bounds__(256) void k_ln(
    const float* __restrict__ P0, const float* __restrict__ P1,
    const float* __restrict__ resid, const float* __restrict__ pbias,
    const float* __restrict__ g, const float* __restrict__ be,
    float* __restrict__ outf, u16* __restrict__ outb, int writeb)
{
    __shared__ float red[2][4];
    const int row = blockIdx.x, t = threadIdx.x;
    const long o = (long)row * 1024 + t * 4;
    float4 a0 = *reinterpret_cast<const float4*>(P0 + o);
    float4 a1 = *reinterpret_cast<const float4*>(P1 + o);
    float4 rr = *reinterpret_cast<const float4*>(resid + o);
    float4 pb = *reinterpret_cast<const float4*>(pbias + t * 4);
    float4 vv;
    vv.x = a0.x + a1.x + rr.x + pb.x;
    vv.y = a0.y + a1.y + rr.y + pb.y;
    vv.z = a0.z + a1.z + rr.z + pb.z;
    vv.w = a0.w + a1.w + rr.w + pb.w;
    float s = vv.x + vv.y + vv.z + vv.w;
    float sq = vv.x * vv.x + vv.y * vv.y + vv.z * vv.z + vv.w * vv.w;
#pragma unroll
    for (int off = 1; off < 64; off <<= 1) {
        s += __shfl_xor(s, off, 64);
        sq += __shfl_xor(sq, off, 64);
    }
    const int w = t >> 6;
    if ((t & 63) == 0) { red[0][w] = s; red[1][w] = sq; }
    __syncthreads();
    s = red[0][0] + red[0][1] + red[0][2] + red[0][3];
    sq = red[1][0] + red[1][1] + red[1][2] + red[1][3];
    const float mu = s * (1.f / 1024.f);
    const float var = sq * (1.f / 1024.f) - mu * mu;
    const float rs = rsqrtf(var + 1e-5f);
    float4 gv = *reinterpret_cast<const float4*>(&g[t * 4]);
    float4 bv = *reinterpret_cast<const float4*>(&be[t * 4]);
    float4 ov;
    ov.x = (vv.x - mu) * rs * gv.x + bv.x;
    ov.y = (vv.y - mu) * rs * gv.y + bv.y;
    ov.z = (vv.z - mu) * rs * gv.z + bv.z;
    ov.w = (vv.w - mu) * rs * gv.w + bv.w;
    *reinterpret_cast<float4*>(&outf[o]) = ov;
    if (writeb) {
        ushort4 ob;
        ob.x = f2b(ov.x); ob.y = f2b(ov.y); ob.z = f2b(ov.z); ob.w = f2b(ov.w);
        *reinterpret_cast<ushort4*>(&outb[o]) = ob;
    }
}

// ---------------- LayerNorm over (4 bf16 partial planes + resid + pbias) ----
__global__ __launch_bounds__(256) void k_ln4b(
    const u16* __restrict__ P, long plane,   // 4 planes at P + z*plane
    const float* __restrict__ resid, const float* __restrict__ pbias,
    const float* __restrict__ g, const float* __restrict__ be,
    float* __restrict__ outf)
{
    __shared__ float red[2][4];
    const int row = blockIdx.x, t = threadIdx.x;
    const long o = (long)row * 1024 + t * 4;
    float4 rr = *reinterpret_cast<const float4*>(resid + o);
    float4 pb = *reinterpret_cast<const float4*>(pbias + t * 4);
    float4 vv;
    vv.x = rr.x + pb.x; vv.y = rr.y + pb.y;
    vv.z = rr.z + pb.z; vv.w = rr.w + pb.w;
#pragma unroll
    for (int z = 0; z < 4; ++z) {
        ushort4 p4 = *reinterpret_cast<const ushort4*>(P + z * plane + o);
        vv.x += b2f(p4.x); vv.y += b2f(p4.y);
        vv.z += b2f(p4.z); vv.w += b2f(p4.w);
    }
    float s = vv.x + vv.y + vv.z + vv.w;
    float sq = vv.x * vv.x + vv.y * vv.y + vv.z * vv.z + vv.w * vv.w;
#pragma unroll
    for (int off = 1; off < 64; off <<= 1) {
        s += __shfl_xor(s, off, 64);
        sq += __shfl_xor(sq, off, 64);
    }
    const int w = t >> 6;
    if ((t & 63) == 0) { red[0][w] = s; red[1][w] = sq; }
    __syncthreads();
    s = red[0][0] + red[0][1] + red[0][2] + red[0][3];
    sq = red[1][0] + red[1][1] + red[1][2] + red[1][3];
    const float mu = s * (1.f / 1024.f);
    const float var = sq * (1.f / 1024.f) - mu * mu;
    const float rs = rsqrtf(var + 1e-5f);
    float4 gv = *reinterpret_cast<const float4*>(&g[t * 4]);
    float4 bv = *reinterpret_cast<const float4*>(&be[t * 4]);
    float4 ov;
    ov.x = (vv.x - mu) * rs * gv.x + bv.x;
    ov.y = (vv.y - mu) * rs * gv.y + bv.y;
    ov.z = (vv.z - mu) * rs * gv.z + bv.z;
    ov.w = (vv.w - mu) * rs * gv.w + bv.w;
    *reinterpret_cast<float4*>(&outf[o]) = ov;
}

extern "C" void kernel_launch(void* const* d_in, const int* in_sizes, int n_in,
                              void* d_out, int out_size, void* d_ws, size_t ws_size,
                              hipStream_t stream)
{
    const float* x  = (const float*)d_in[0];
    const float* Wq = (const float*)d_in[2];  const float* bq = (const float*)d_in[3];
    const float* Wk = (const float*)d_in[4];  const float* bk = (const float*)d_in[5];
    const float* Wv = (const float*)d_in[6];  const float* bv = (const float*)d_in[7];
    const float* Wo = (const float*)d_in[8];  const float* bo = (const float*)d_in[9];
    const float* W1 = (const float*)d_in[10]; const float* b1 = (const float*)d_in[11];
    const float* W2 = (const float*)d_in[12]; const float* b2 = (const float*)d_in[13];
    const float* g1 = (const float*)d_in[14]; const float* be1 = (const float*)d_in[15];
    const float* g2 = (const float*)d_in[16]; const float* be2 = (const float*)d_in[17];
    float* out = (float*)d_out;

    // ---- workspace layout (peak 104MB) ----
    char* ws = (char*)d_ws;
    const size_t MB = 1 << 20;
    u16* XB   = (u16*)(ws + 0 * MB);     // 8MB : convert -> QKV gemm
    u16* QKVT = (u16*)(ws + 8 * MB);     // 6MB
    u16* WOT  = (u16*)(ws + 14 * MB);    // 2MB
    u16* W1T  = (u16*)(ws + 16 * MB);    // 8MB (dead after FF1)
    u16* W2T  = (u16*)(ws + 96 * MB);    // 8MB (96-104)
    u16* QKV  = (u16*)(ws + 32 * MB);    // 24MB packed Q'/K'/V'
    u16* AT   = (u16*)(ws + 64 * MB);    // 8MB attn out
    float* OP = (float*)(ws + 32 * MB);  // 32MB out-proj f32 partials (over dead QKV)
    float* Y1 = (float*)(ws + 0 * MB);   // 16MB LN1 out f32 (over dead XB/QKVT/WOT)
    u16* Y1B  = (u16*)(ws + 64 * MB);    // 8MB LN1 out bf16 (over dead AT)
    u16* Hb   = (u16*)(ws + 24 * MB);    // 32MB FF1 out (over dead OP tail/QKV)
    u16* FPB  = (u16*)(ws + 56 * MB);    // 32MB FF2 bf16 partials x4 (56-88)

    u16* Qb = QKV;
    u16* Kb = QKV + 32L * 2048 * 64;
    u16* Vb = QKV + 2 * 32L * 2048 * 64;

    dim3 blk(256);

    k_convert_bf16<<<dim3(4096), blk, 0, stream>>>(x, XB, 4096 * 1024);
    k_transpose_w<<<dim3(32, 32), blk, 0, stream>>>(Wq, QKVT, 1024, 1024);
    k_transpose_w<<<dim3(32, 32), blk, 0, stream>>>(Wk, QKVT + 1024L * 1024, 1024, 1024);
    k_transpose_w<<<dim3(32, 32), blk, 0, stream>>>(Wv, QKVT + 2048L * 1024, 1024, 1024);
    k_transpose_w<<<dim3(32, 32), blk, 0, stream>>>(Wo, WOT, 1024, 1024);
    k_transpose_w<<<dim3(128, 32), blk, 0, stream>>>(W1, W1T, 1024, 4096);
    k_transpose_w<<<dim3(32, 128), blk, 0, stream>>>(W2, W2T, 4096, 1024);

    // fused QKV projection: 2-phase 128^2, packed Q'/K'/V'. patch (4,2)
    k_gemm<0><<<dim3(24, 32), blk, 0, stream>>>(XB, QKVT, bq, bk, bv,
                                                QKV, nullptr, 4096, 3072, 1024, 4, 2);

    k_attn4<<<dim3(1024), blk, 0, stream>>>(Qb, Kb, Vb, AT);

    // attn out-proj: 256x128 counted-vmcnt, split-K=2, patch (2,4) -> LN1
    k_gemm8n<<<dim3(8, 16, 2), dim3(512), 0, stream>>>(AT, WOT, OP,
                                                       4096, 1024, 1024, 2, 4);
    k_ln<<<dim3(4096), blk, 0, stream>>>(OP, OP + 4096L * 1024, x, bo,
                                         g1, be1, Y1, Y1B, 1);
    // FF1: 256x256 counted-vmcnt 4-phase, grid 16x16 (1/CU), patch (2,4)
    k_gemm8<0><<<dim3(16, 16), dim3(512), 0, stream>>>(Y1B, W1T, b1, Hb,
                                                       4096, 4096, 1024, 2, 4);
    // FF2: 256x256 counted-vmcnt 4-phase, split-K=4 (grid 4x16x4 = 256 = 1/CU),
    // bf16 partial planes -> k_ln4b. patch (4,2).
    k_gemm8<1><<<dim3(4, 16, 4), dim3(512), 0, stream>>>(Hb, W2T, nullptr, FPB,
                                                         4096, 1024, 4096, 4, 2);
    k_ln4b<<<dim3(4096), blk, 0, stream>>>(FPB, 4096L * 1024, Y1, b2,
                                           g2, be2, out);
}